// Round 6
// baseline (398.371 us; speedup 1.0000x reference)
//
#include <hip/hip_runtime.h>
#include <hip/hip_bf16.h>
#include <stdint.h>

// Problem constants
#define B_   512
#define T_   87
#define C_   512
#define H_   8
#define D_   64
#define BT_  44544        // B_*T_

typedef __attribute__((ext_vector_type(4))) float f32x4;
typedef __attribute__((ext_vector_type(8))) __bf16 bf16x8;
typedef __attribute__((ext_vector_type(4))) unsigned short u16x4;

__device__ __forceinline__ int mod29(int x) {
  return x < 29 ? x : (x < 58 ? x - 29 : x - 58);
}

// ---------------- W convert (fp32 -> bf16, once) ----------------
__global__ void convert_w_kernel(const float* __restrict__ Wq, const float* __restrict__ Wk,
                                 const float* __restrict__ Wv, const float* __restrict__ Wp,
                                 __hip_bfloat16* __restrict__ wqkv,
                                 __hip_bfloat16* __restrict__ wp) {
  const int NW = 262144;                 // 512*512
  const int total = 4 * NW;
  int stride = gridDim.x * blockDim.x;
  for (int i = blockIdx.x * blockDim.x + threadIdx.x; i < total; i += stride) {
    if (i < 3 * NW) {
      float v = (i < NW) ? Wq[i] : (i < 2 * NW ? Wk[i - NW] : Wv[i - 2 * NW]);
      wqkv[i] = __float2bfloat16(v);
    } else {
      wp[i - 3 * NW] = __float2bfloat16(Wp[i - 3 * NW]);
    }
  }
}

// ---------------- fused per-batch kernel ----------------
// LDS map (bytes):
//  X  [96][512] bf16, 1024B rows, 16B-chunk c stored at c^(row&7) : [0, 98304)
//  Q  [96][64]  bf16, 128B rows, chunk^(row&7)                    : [98304, 110592)
//  K  [96][64]                                                    : [110592, 122880)
//  P  [96][96]  bf16, 192B rows, chunk^(row&3)  (aliases Q,K)     : [98304, 116736)
//  Vt [64][96]  bf16, 192B rows, chunk^(row&3)                    : [122880, 135168)
//  Y  [96][64]  bf16, 128B rows, chunk^(row&7)  (aliases Vt)      : [122880, 135168)
#define XO  0
#define QO  98304
#define KO  110592
#define PO  98304
#define VTO 122880
#define YO  122880
#define SMEM_BYTES 135168

__global__ __launch_bounds__(512) void fused_kernel(
    const float* __restrict__ x,
    const __hip_bfloat16* __restrict__ wqkv,   // [1536][512] rows: q,k,v
    const __hip_bfloat16* __restrict__ wp,     // [512][512]
    const float* __restrict__ bq, const float* __restrict__ bk,
    const float* __restrict__ bv, const float* __restrict__ bp,
    float* __restrict__ out) {
  __shared__ __align__(16) char smem[SMEM_BYTES];

  const int tid = threadIdx.x, lane = tid & 63, wave = tid >> 6;
  const int r16 = lane & 15, r4 = lane >> 4;
  const int b = blockIdx.x;

  // ---- stage x_b: fp32 global -> bf16 LDS (swizzled), pad rows 87..95 = 0 ----
  {
    const float* xg = x + (size_t)b * (87 * 512);
    for (int i = tid; i < 12288; i += 512) {        // 96 rows * 128 f32x4
      int row = i >> 7, c4 = i & 127;
      f32x4 v = {0.f, 0.f, 0.f, 0.f};
      if (row < 87) v = *(const f32x4*)(xg + row * 512 + c4 * 4);
      u16x4 o;
      o.x = __builtin_bit_cast(unsigned short, __float2bfloat16(v.x));
      o.y = __builtin_bit_cast(unsigned short, __float2bfloat16(v.y));
      o.z = __builtin_bit_cast(unsigned short, __float2bfloat16(v.z));
      o.w = __builtin_bit_cast(unsigned short, __float2bfloat16(v.w));
      int addr = XO + row * 1024 + (((c4 >> 1) ^ (row & 7)) << 4) + ((c4 & 1) << 3);
      *(u16x4*)(smem + addr) = o;
    }
  }

  // wave geometry
  const int wm = wave >> 2, wn = wave & 3;    // QK gemm: 2M x 4N, wave = [48 m][32 n]
  const int mtv = wave >> 1, ntv = wave & 1;  // Vt gemm: 4M x 2N, wave = [16 d][48 j]
  const int pm = wave >> 2, pn = wave & 3;    // proj:    2M x 4N, wave = [48 m][128 n]

  // proj accumulator (held across all heads)
  f32x4 pacc[3][8] = {};
  float bpv[8];
#pragma unroll
  for (int fn = 0; fn < 8; ++fn) bpv[fn] = bp[pn * 128 + fn * 16 + r16];

  // precomputed X row info for QK A-frags and Vt B-frags
  int xarow[3], xbrow[3];
#pragma unroll
  for (int f = 0; f < 3; ++f) {
    xarow[f] = wm * 48 + f * 16 + r16;
    xbrow[f] = ntv * 48 + f * 16 + r16;
  }

  __syncthreads();   // x staged

  for (int h = 0; h < 8; ++h) {
    // ======== QKV GEMMs (barrier-free; W direct from L2) ========
    // B-frag row pointers (per-lane)
    const char* qkB[2];
#pragma unroll
    for (int fn = 0; fn < 2; ++fn) {
      int c = wn * 32 + fn * 16 + r16;                    // 0..127
      int grow = (c < 64) ? (h * 64 + c) : (512 + h * 64 + (c - 64));
      qkB[fn] = (const char*)wqkv + (size_t)grow * 1024;
    }
    const char* vA = (const char*)wqkv + (size_t)(1024 + h * 64 + mtv * 16 + r16) * 1024;

    f32x4 qk[3][2] = {};
    f32x4 vt[3] = {};
#pragma unroll 4
    for (int kt = 0; kt < 16; ++kt) {
      bf16x8 bw[2], aw;
#pragma unroll
      for (int fn = 0; fn < 2; ++fn)
        bw[fn] = *(const bf16x8*)(qkB[fn] + kt * 64 + r4 * 16);
      aw = *(const bf16x8*)(vA + kt * 64 + r4 * 16);
      bf16x8 ax[3], bx[3];
#pragma unroll
      for (int f = 0; f < 3; ++f) {
        ax[f] = *(const bf16x8*)(smem + XO + xarow[f] * 1024 +
                                 (((kt * 4 + r4) ^ (xarow[f] & 7)) << 4));
        bx[f] = *(const bf16x8*)(smem + XO + xbrow[f] * 1024 +
                                 (((kt * 4 + r4) ^ (xbrow[f] & 7)) << 4));
      }
#pragma unroll
      for (int fm = 0; fm < 3; ++fm)
#pragma unroll
        for (int fn = 0; fn < 2; ++fn)
          qk[fm][fn] = __builtin_amdgcn_mfma_f32_16x16x32_bf16(ax[fm], bw[fn], qk[fm][fn], 0, 0, 0);
#pragma unroll
      for (int jn = 0; jn < 3; ++jn)
        vt[jn] = __builtin_amdgcn_mfma_f32_16x16x32_bf16(aw, bx[jn], vt[jn], 0, 0, 0);
    }

    // epilogue: Q/K -> LDS (+bias), Vt -> LDS (+bias)
#pragma unroll
    for (int fn = 0; fn < 2; ++fn) {
      int c = wn * 32 + fn * 16 + r16;
      float bb = (c < 64) ? bq[h * 64 + c] : bk[h * 64 + (c - 64)];
      int base = (c < 64) ? QO : KO;
      int cc = c & 63;
#pragma unroll
      for (int fm = 0; fm < 3; ++fm) {
#pragma unroll
        for (int rr = 0; rr < 4; ++rr) {
          int row = wm * 48 + fm * 16 + r4 * 4 + rr;
          int addr = base + row * 128 + (((cc >> 3) ^ (row & 7)) << 4) + ((cc & 7) << 1);
          *(__hip_bfloat16*)(smem + addr) = __float2bfloat16(qk[fm][fn][rr] + bb);
        }
      }
    }
#pragma unroll
    for (int rr = 0; rr < 4; ++rr) {
      int d = mtv * 16 + r4 * 4 + rr;
      float bb = bv[h * 64 + d];
#pragma unroll
      for (int jn = 0; jn < 3; ++jn) {
        int j = ntv * 48 + jn * 16 + r16;
        int addr = VTO + d * 192 + (((j >> 3) ^ (d & 3)) << 4) + ((j & 7) << 1);
        *(__hip_bfloat16*)(smem + addr) = __float2bfloat16(vt[jn][rr] + bb);
      }
    }
    __syncthreads();   // B1: Q,K,Vt visible

    // ======== QK^T + in-register masked softmax -> P (waves 0..5) ========
    if (wave < 6) {
      f32x4 s[6] = {};
#pragma unroll
      for (int kk = 0; kk < 2; ++kk) {
        int arow = wave * 16 + r16;
        bf16x8 aq = *(const bf16x8*)(smem + QO + arow * 128 +
                                     (((kk * 4 + r4) ^ (arow & 7)) << 4));
#pragma unroll
        for (int j = 0; j < 6; ++j) {
          int brow = j * 16 + r16;
          bf16x8 kb = *(const bf16x8*)(smem + KO + brow * 128 +
                                       (((kk * 4 + r4) ^ (brow & 7)) << 4));
          s[j] = __builtin_amdgcn_mfma_f32_16x16x32_bf16(aq, kb, s[j], 0, 0, 0);
        }
      }
      int lr_[4]; bool rok_[4];
      float mx_[4], sum_[4], inv_[4];
#pragma unroll
      for (int rr = 0; rr < 4; ++rr) {
        int row = wave * 16 + r4 * 4 + rr;
        rok_[rr] = row < 87;
        lr_[rr] = mod29(row);
        mx_[rr] = -1e30f;
        sum_[rr] = 0.f;
      }
#pragma unroll
      for (int j = 0; j < 6; ++j) {
        int col = j * 16 + r16;
        int lc = mod29(col);
        bool cok = col < 87;
#pragma unroll
        for (int rr = 0; rr < 4; ++rr) {
          bool al = rok_[rr] && cok && (lc <= lr_[rr]) && (lc + 21 >= lr_[rr]);
          float sv = al ? s[j][rr] * 0.125f : -1e30f;
          s[j][rr] = sv;
          mx_[rr] = fmaxf(mx_[rr], sv);
        }
      }
#pragma unroll
      for (int rr = 0; rr < 4; ++rr) {
        mx_[rr] = fmaxf(mx_[rr], __shfl_xor(mx_[rr], 1));
        mx_[rr] = fmaxf(mx_[rr], __shfl_xor(mx_[rr], 2));
        mx_[rr] = fmaxf(mx_[rr], __shfl_xor(mx_[rr], 4));
        mx_[rr] = fmaxf(mx_[rr], __shfl_xor(mx_[rr], 8));
      }
#pragma unroll
      for (int j = 0; j < 6; ++j)
#pragma unroll
        for (int rr = 0; rr < 4; ++rr) {
          float e = __expf(s[j][rr] - mx_[rr]);
          s[j][rr] = e;
          sum_[rr] += e;
        }
#pragma unroll
      for (int rr = 0; rr < 4; ++rr) {
        sum_[rr] += __shfl_xor(sum_[rr], 1);
        sum_[rr] += __shfl_xor(sum_[rr], 2);
        sum_[rr] += __shfl_xor(sum_[rr], 4);
        sum_[rr] += __shfl_xor(sum_[rr], 8);
        inv_[rr] = rok_[rr] ? (1.f / sum_[rr]) : 0.f;
      }
#pragma unroll
      for (int j = 0; j < 6; ++j) {
        int col = j * 16 + r16;
#pragma unroll
        for (int rr = 0; rr < 4; ++rr) {
          int row = wave * 16 + r4 * 4 + rr;
          int addr = PO + row * 192 + (((col >> 3) ^ (row & 3)) << 4) + ((col & 7) << 1);
          *(__hip_bfloat16*)(smem + addr) = __float2bfloat16(s[j][rr] * inv_[rr]);
        }
      }
    }
    __syncthreads();   // B2: P visible

    // ======== PV: y = P @ Vt  (24 frag jobs over 8 waves) ========
    f32x4 yac[3] = {};
#pragma unroll
    for (int i = 0; i < 3; ++i) {
      int f = wave + 8 * i;
      int mt = f >> 2, nt = f & 3;
#pragma unroll
      for (int kk = 0; kk < 3; ++kk) {
        int arow = mt * 16 + r16;
        int brow = nt * 16 + r16;
        bf16x8 a = *(const bf16x8*)(smem + PO + arow * 192 +
                                    (((kk * 4 + r4) ^ (arow & 3)) << 4));
        bf16x8 bb = *(const bf16x8*)(smem + VTO + brow * 192 +
                                     (((kk * 4 + r4) ^ (brow & 3)) << 4));
        yac[i] = __builtin_amdgcn_mfma_f32_16x16x32_bf16(a, bb, yac[i], 0, 0, 0);
      }
    }
    __syncthreads();   // B3: all Vt reads done (Y aliases Vt)

#pragma unroll
    for (int i = 0; i < 3; ++i) {
      int f = wave + 8 * i;
      int mt = f >> 2, nt = f & 3;
#pragma unroll
      for (int rr = 0; rr < 4; ++rr) {
        int m = mt * 16 + r4 * 4 + rr;
        int d = nt * 16 + r16;
        int addr = YO + m * 128 + (((d >> 3) ^ (m & 7)) << 4) + ((d & 7) << 1);
        *(__hip_bfloat16*)(smem + addr) = __float2bfloat16(yac[i][rr]);
      }
    }
    __syncthreads();   // B4: y visible

    // ======== proj accumulate: out += y_h @ Wp[:, h*64:(h+1)*64]^T ========
    {
      const char* pB = (const char*)wp + (size_t)(pn * 128 + r16) * 1024 + h * 128;
#pragma unroll
      for (int kk = 0; kk < 2; ++kk) {
        bf16x8 af[3];
#pragma unroll
        for (int fm = 0; fm < 3; ++fm) {
          int row = pm * 48 + fm * 16 + r16;
          af[fm] = *(const bf16x8*)(smem + YO + row * 128 +
                                    (((kk * 4 + r4) ^ (row & 7)) << 4));
        }
#pragma unroll
        for (int fn = 0; fn < 8; ++fn) {
          bf16x8 bf_ = *(const bf16x8*)(pB + (size_t)fn * 16384 + kk * 64 + r4 * 16);
#pragma unroll
          for (int fm = 0; fm < 3; ++fm)
            pacc[fm][fn] = __builtin_amdgcn_mfma_f32_16x16x32_bf16(af[fm], bf_, pacc[fm][fn], 0, 0, 0);
        }
      }
    }
    __syncthreads();   // B0 for next head: proj reads of Y done, regions free
  }

  // ======== epilogue: out = pacc + bp ========
#pragma unroll
  for (int fm = 0; fm < 3; ++fm) {
#pragma unroll
    for (int rr = 0; rr < 4; ++rr) {
      int m = pm * 48 + fm * 16 + r4 * 4 + rr;
      if (m < 87) {
        float* orow = out + ((size_t)b * 87 + m) * 512;
#pragma unroll
        for (int fn = 0; fn < 8; ++fn) {
          int n = pn * 128 + fn * 16 + r16;
          orow[n] = pacc[fm][fn][rr] + bpv[fn];
        }
      }
    }
  }
}

// ---------------- launch ----------------
extern "C" void kernel_launch(void* const* d_in, const int* in_sizes, int n_in,
                              void* d_out, int out_size, void* d_ws, size_t ws_size,
                              hipStream_t stream) {
  const float* x  = (const float*)d_in[0];
  const float* Wq = (const float*)d_in[1];
  const float* bq = (const float*)d_in[2];
  const float* Wk = (const float*)d_in[3];
  const float* bk = (const float*)d_in[4];
  const float* Wv = (const float*)d_in[5];
  const float* bv = (const float*)d_in[6];
  const float* Wp = (const float*)d_in[7];
  const float* bp = (const float*)d_in[8];
  float* out = (float*)d_out;

  char* ws = (char*)d_ws;
  size_t off = 0;
  __hip_bfloat16* wqkv = (__hip_bfloat16*)(ws + off); off += (size_t)1536 * 512 * 2;
  __hip_bfloat16* wp   = (__hip_bfloat16*)(ws + off); off += (size_t)512 * 512 * 2;
  if (ws_size < off) return;

  convert_w_kernel<<<1024, 256, 0, stream>>>(Wq, Wk, Wv, Wp, wqkv, wp);
  fused_kernel<<<B_, 512, 0, stream>>>(x, wqkv, wp, bq, bk, bv, bp, out);
}

// Round 7
// 323.653 us; speedup vs baseline: 1.2309x; 1.2309x over previous
//
#include <hip/hip_runtime.h>
#include <hip/hip_bf16.h>
#include <stdint.h>

// Problem constants
#define B_   512
#define T_   87
#define C_   512
#define H_   8
#define D_   64
#define BT_  44544        // B_*T_
#define BH_  4096         // B_*H_

typedef __attribute__((ext_vector_type(4))) float f32x4;
typedef __attribute__((ext_vector_type(8))) __bf16 bf16x8;
typedef __attribute__((ext_vector_type(4))) unsigned short u16x4;

__device__ __forceinline__ int mod29(int x) {
  return x < 29 ? x : (x < 58 ? x - 29 : x - 58);
}

// ---------------- converts ----------------

__global__ void convert_x_kernel(const float* __restrict__ x,
                                 __hip_bfloat16* __restrict__ xb, int n4) {
  int stride = gridDim.x * blockDim.x;
  for (int i = blockIdx.x * blockDim.x + threadIdx.x; i < n4; i += stride) {
    f32x4 v = ((const f32x4*)x)[i];
    u16x4 o;
    o.x = __builtin_bit_cast(unsigned short, __float2bfloat16(v.x));
    o.y = __builtin_bit_cast(unsigned short, __float2bfloat16(v.y));
    o.z = __builtin_bit_cast(unsigned short, __float2bfloat16(v.z));
    o.w = __builtin_bit_cast(unsigned short, __float2bfloat16(v.w));
    ((u16x4*)xb)[i] = o;
  }
}

__global__ void convert_w_kernel(const float* __restrict__ Wq, const float* __restrict__ Wk,
                                 const float* __restrict__ Wv, const float* __restrict__ Wp,
                                 const float* __restrict__ bq, const float* __restrict__ bk,
                                 const float* __restrict__ bv,
                                 __hip_bfloat16* __restrict__ wqkv,
                                 __hip_bfloat16* __restrict__ wp,
                                 float* __restrict__ biasc) {
  const int NW = 262144;                 // 512*512
  const int total = 3 * NW + NW + 1536;
  int stride = gridDim.x * blockDim.x;
  for (int i = blockIdx.x * blockDim.x + threadIdx.x; i < total; i += stride) {
    if (i < 3 * NW) {
      float v = (i < NW) ? Wq[i] : (i < 2 * NW ? Wk[i - NW] : Wv[i - 2 * NW]);
      wqkv[i] = __float2bfloat16(v);
    } else if (i < 4 * NW) {
      wp[i - 3 * NW] = __float2bfloat16(Wp[i - 3 * NW]);
    } else {
      int j = i - 4 * NW;
      biasc[j] = (j < 512) ? bq[j] : (j < 1024 ? bk[j - 512] : bv[j - 1024]);
    }
  }
}

// zero the pad rows (t = 87..95) of q/k and pad cols of vt
__global__ void zero_pads_kernel(__hip_bfloat16* __restrict__ q_ws,
                                 __hip_bfloat16* __restrict__ k_ws,
                                 __hip_bfloat16* __restrict__ vt_ws) {
  const int per = BH_ * 576;  // 9*64 pad elems per (b,h)
  int stride = gridDim.x * blockDim.x;
  __hip_bfloat16 z = __float2bfloat16(0.f);
  for (int i = blockIdx.x * blockDim.x + threadIdx.x; i < 3 * per; i += stride) {
    if (i < per) {
      int bh = i / 576, rem = i - (i / 576) * 576;
      q_ws[(size_t)bh * 6144 + 5568 + rem] = z;
    } else if (i < 2 * per) {
      int j = i - per;
      int bh = j / 576, rem = j - (j / 576) * 576;
      k_ws[(size_t)bh * 6144 + 5568 + rem] = z;
    } else {
      int j = i - 2 * per;
      int bh = j / 576, rem = j - (j / 576) * 576;
      int d = rem / 9, o = rem - d * 9;
      vt_ws[(size_t)bh * 6144 + d * 96 + 87 + o] = z;
    }
  }
}

// ---------------- reg-staged GEMM (T14), 128x128 tile, BK=64, 4 waves ----------
// LDS: 2 buffers x (A 16KB + B 16KB) = 64KB -> 2 blocks/CU.
// Swizzle on ds_write: 16B slot s of row r holds global chunk s^(r&7).

// one BK=64 K-tile: acc[FM][FN] += A[wbM..][k] * B[wbN..][k]^T  (128B rows)
template<int FM, int FN>
__device__ __forceinline__ void compute_tile(const char* Ab, const char* Bb,
                                             int wbM, int wbN, int r16, int r4,
                                             f32x4 acc[FM][FN]) {
  const int cxor = (r16 & 7) << 4;   // row&7 == r16&7 (bases are multiples of 16)
  bf16x8 bf[FN][2];
#pragma unroll
  for (int fn = 0; fn < FN; ++fn) {
    int row = wbN + fn * 16 + r16;
#pragma unroll
    for (int kk = 0; kk < 2; ++kk)
      bf[fn][kk] = *(const bf16x8*)(Bb + row * 128 + ((kk * 64 + r4 * 16) ^ cxor));
  }
#pragma unroll
  for (int fm = 0; fm < FM; ++fm) {
    int row = wbM + fm * 16 + r16;
    bf16x8 a0 = *(const bf16x8*)(Ab + row * 128 + ((r4 * 16) ^ cxor));
    bf16x8 a1 = *(const bf16x8*)(Ab + row * 128 + ((64 + r4 * 16) ^ cxor));
#pragma unroll
    for (int fn = 0; fn < FN; ++fn) {
      acc[fm][fn] = __builtin_amdgcn_mfma_f32_16x16x32_bf16(a0, bf[fn][0], acc[fm][fn], 0, 0, 0);
      acc[fm][fn] = __builtin_amdgcn_mfma_f32_16x16x32_bf16(a1, bf[fn][1], acc[fm][fn], 0, 0, 0);
    }
  }
}

// EPI 0: qkv scatter (o0=q,o1=k,o2=vt, bias=biasc). EPI 1: proj fp32 (o0=out).
template<int EPI>
__global__ __launch_bounds__(256) void gemmr_kernel(
    const __hip_bfloat16* __restrict__ A, const __hip_bfloat16* __restrict__ Bt,
    const float* __restrict__ bias, int ntn,
    void* __restrict__ o0, void* __restrict__ o1, void* __restrict__ o2) {
  __shared__ __align__(16) char smem[2][2][16384];  // [buf][A|B][128 rows x 128B]

  int tid = threadIdx.x, lane = tid & 63, wave = tid >> 6;
  int r16 = lane & 15, r4 = lane >> 4;

  // XCD swizzle (grid divisible by 8 by construction)
  int nwg = gridDim.x;
  int wg = (blockIdx.x & 7) * (nwg >> 3) + (blockIdx.x >> 3);
  int tileM = (wg / ntn) * 128, tileN = (wg % ntn) * 128;

  int wr = wave >> 1, wc = wave & 1;       // per-wave 64x64
  int wbM = wr * 64, wbN = wc * 64;

  // staging geometry: thread t covers rows (t>>3)+32j (j=0..3), chunk c=t&7
  const int rbase = tid >> 3, c = tid & 7;
  const int cs = (c ^ (rbase & 7)) << 4;   // swizzled byte slot (row&7 == rbase&7)
  const char* Ag = (const char*)A + (size_t)(tileM + rbase) * 1024 + c * 16;
  const char* Bg = (const char*)Bt + (size_t)(tileN + rbase) * 1024 + c * 16;

  f32x4 acc[4][4] = {};
  bf16x8 rA[4], rB[4];

  // prologue: tile 0 -> regs -> LDS buf0
#pragma unroll
  for (int j = 0; j < 4; ++j) {
    rA[j] = *(const bf16x8*)(Ag + (size_t)j * 32768);
    rB[j] = *(const bf16x8*)(Bg + (size_t)j * 32768);
  }
#pragma unroll
  for (int j = 0; j < 4; ++j) {
    *(bf16x8*)(&smem[0][0][0] + (rbase + 32 * j) * 128 + cs) = rA[j];
    *(bf16x8*)(&smem[0][1][0] + (rbase + 32 * j) * 128 + cs) = rB[j];
  }
  __syncthreads();

#pragma unroll
  for (int kt = 0; kt < 8; ++kt) {
    int cur = kt & 1;
    if (kt < 7) {  // issue next-tile global loads EARLY (latency hides under MFMA)
#pragma unroll
      for (int j = 0; j < 4; ++j) {
        rA[j] = *(const bf16x8*)(Ag + (size_t)j * 32768 + (kt + 1) * 128);
        rB[j] = *(const bf16x8*)(Bg + (size_t)j * 32768 + (kt + 1) * 128);
      }
    }
    __builtin_amdgcn_s_setprio(1);
    compute_tile<4, 4>(&smem[cur][0][0], &smem[cur][1][0], wbM, wbN, r16, r4, acc);
    __builtin_amdgcn_s_setprio(0);
    if (kt < 7) {  // write LATE into the other buffer (consumed fully last iter)
#pragma unroll
      for (int j = 0; j < 4; ++j) {
        *(bf16x8*)(&smem[cur ^ 1][0][0] + (rbase + 32 * j) * 128 + cs) = rA[j];
        *(bf16x8*)(&smem[cur ^ 1][1][0] + (rbase + 32 * j) * 128 + cs) = rB[j];
      }
    }
    __syncthreads();  // writes visible; reads of cur done before next overwrite
  }

  // epilogue: C/D layout col=lane&15, row=(lane>>4)*4+reg [m89-verified]
#pragma unroll
  for (int fm = 0; fm < 4; ++fm) {
    int gmb = tileM + wbM + fm * 16 + r4 * 4;
#pragma unroll
    for (int fn = 0; fn < 4; ++fn) {
      int gn = tileN + wbN + fn * 16 + r16;
      float bv = bias[gn];
      if constexpr (EPI == 0) {
        int sel = gn >> 9;          // 0=q, 1=k, 2=v
        int n2 = gn & 511;
        int hh = n2 >> 6, dd = n2 & 63;
#pragma unroll
        for (int rr = 0; rr < 4; ++rr) {
          int gm = gmb + rr;
          int bb = gm / 87, tt = gm - bb * 87;
          __hip_bfloat16 hv = __float2bfloat16(acc[fm][fn][rr] + bv);
          if (sel == 0)
            ((__hip_bfloat16*)o0)[((size_t)(bb * 8 + hh) * 96 + tt) * 64 + dd] = hv;
          else if (sel == 1)
            ((__hip_bfloat16*)o1)[((size_t)(bb * 8 + hh) * 96 + tt) * 64 + dd] = hv;
          else
            ((__hip_bfloat16*)o2)[((size_t)(bb * 8 + hh) * 64 + dd) * 96 + tt] = hv;
        }
      } else {
#pragma unroll
        for (int rr = 0; rr < 4; ++rr)
          ((float*)o0)[(size_t)(gmb + rr) * 512 + gn] = acc[fm][fn][rr] + bv;
      }
    }
  }
}

// ---------------- attention per (b,h) (unchanged) ----------------
__global__ __launch_bounds__(256) void attn_kernel(
    const __hip_bfloat16* __restrict__ q_ws, const __hip_bfloat16* __restrict__ k_ws,
    const __hip_bfloat16* __restrict__ vt_ws, __hip_bfloat16* __restrict__ y_ws) {
  __shared__ __align__(16) char smem[73728];
  __hip_bfloat16* Qs  = (__hip_bfloat16*)smem;             // [96][64] 12KB
  __hip_bfloat16* Ks  = (__hip_bfloat16*)(smem + 12288);   // [96][64] 12KB
  __hip_bfloat16* Vts = (__hip_bfloat16*)(smem + 24576);   // [64][96] 12KB
  float* Sb           = (float*)(smem + 36864);            // [96][96] fp32 36KB
  __hip_bfloat16* Pb  = (__hip_bfloat16*)smem;             // [96][96] aliases Qs+Ks

  int tid = threadIdx.x, lane = tid & 63, wave = tid >> 6;
  int bh = blockIdx.x, b = bh >> 3, h = bh & 7;
  int r16 = lane & 15, r4 = lane >> 4;

  {
    const bf16x8* gq = (const bf16x8*)(q_ws + (size_t)bh * 6144);
    const bf16x8* gk = (const bf16x8*)(k_ws + (size_t)bh * 6144);
    const bf16x8* gv = (const bf16x8*)(vt_ws + (size_t)bh * 6144);
    bf16x8* lq = (bf16x8*)Qs; bf16x8* lk = (bf16x8*)Ks; bf16x8* lv = (bf16x8*)Vts;
    for (int i = tid; i < 768; i += 256) { lq[i] = gq[i]; lk[i] = gk[i]; lv[i] = gv[i]; }
  }
  __syncthreads();

  // S = Q K^T : 6x6 16-tiles, K=64
  for (int p = 0; p < 9; ++p) {
    int pair = wave + p * 4;
    int mt = pair / 6, nt = pair - mt * 6;
    f32x4 acc = {0.f, 0.f, 0.f, 0.f};
#pragma unroll
    for (int kk = 0; kk < 2; ++kk) {
      bf16x8 a  = *(const bf16x8*)(Qs + (mt * 16 + r16) * 64 + kk * 32 + r4 * 8);
      bf16x8 bb = *(const bf16x8*)(Ks + (nt * 16 + r16) * 64 + kk * 32 + r4 * 8);
      acc = __builtin_amdgcn_mfma_f32_16x16x32_bf16(a, bb, acc, 0, 0, 0);
    }
    int row0 = mt * 16 + r4 * 4, col = nt * 16 + r16;
#pragma unroll
    for (int r = 0; r < 4; ++r) Sb[(row0 + r) * 96 + col] = acc[r];
  }
  __syncthreads();

  // masked softmax, one 32-lane group per row
  int group = tid >> 5, glane = tid & 31;
  for (int r = group; r < 96; r += 8) {
    if (r < 87) {
      int lr = mod29(r);
      float sv[3]; bool al[3];
      float mx = -__builtin_inff();
#pragma unroll
      for (int q = 0; q < 3; ++q) {
        int j = glane + q * 32;
        int lj = mod29(j);
        al[q] = (j < 87) && (lj <= lr) && (lj >= lr - 21);
        sv[q] = al[q] ? Sb[r * 96 + j] * 0.125f : -__builtin_inff();
        mx = fmaxf(mx, sv[q]);
      }
#pragma unroll
      for (int o = 16; o >= 1; o >>= 1) mx = fmaxf(mx, __shfl_xor(mx, o, 32));
      float e[3], sum = 0.f;
#pragma unroll
      for (int q = 0; q < 3; ++q) { e[q] = al[q] ? __expf(sv[q] - mx) : 0.f; sum += e[q]; }
#pragma unroll
      for (int o = 16; o >= 1; o >>= 1) sum += __shfl_xor(sum, o, 32);
      float inv = 1.f / sum;
#pragma unroll
      for (int q = 0; q < 3; ++q)
        Pb[r * 96 + glane + q * 32] = __float2bfloat16(e[q] * inv);
    } else {
#pragma unroll
      for (int q = 0; q < 3; ++q) Pb[r * 96 + glane + q * 32] = __float2bfloat16(0.f);
    }
  }
  __syncthreads();

  // Y = P V : A=P [96][96], Bt=Vt [64][96], 6x4 16-tiles, K=96
  for (int p = 0; p < 6; ++p) {
    int pair = wave + p * 4;
    int mt = pair >> 2, nt = pair & 3;
    f32x4 acc = {0.f, 0.f, 0.f, 0.f};
#pragma unroll
    for (int kk = 0; kk < 3; ++kk) {
      bf16x8 a  = *(const bf16x8*)(Pb + (mt * 16 + r16) * 96 + kk * 32 + r4 * 8);
      bf16x8 bb = *(const bf16x8*)(Vts + (nt * 16 + r16) * 96 + kk * 32 + r4 * 8);
      acc = __builtin_amdgcn_mfma_f32_16x16x32_bf16(a, bb, acc, 0, 0, 0);
    }
    int t0 = mt * 16 + r4 * 4, d = nt * 16 + r16;
#pragma unroll
    for (int r = 0; r < 4; ++r) {
      int t = t0 + r;
      if (t < 87)
        y_ws[((size_t)b * 87 + t) * 512 + h * 64 + d] = __float2bfloat16(acc[r]);
    }
  }
}

// ---------------- launch ----------------
extern "C" void kernel_launch(void* const* d_in, const int* in_sizes, int n_in,
                              void* d_out, int out_size, void* d_ws, size_t ws_size,
                              hipStream_t stream) {
  const float* x  = (const float*)d_in[0];
  const float* Wq = (const float*)d_in[1];
  const float* bq = (const float*)d_in[2];
  const float* Wk = (const float*)d_in[3];
  const float* bk = (const float*)d_in[4];
  const float* Wv = (const float*)d_in[5];
  const float* bv = (const float*)d_in[6];
  const float* Wp = (const float*)d_in[7];
  const float* bp = (const float*)d_in[8];
  float* out = (float*)d_out;

  char* ws = (char*)d_ws;
  size_t off = 0;
  __hip_bfloat16* xb    = (__hip_bfloat16*)(ws + off); off += (size_t)BT_ * 512 * 2;
  __hip_bfloat16* wqkv  = (__hip_bfloat16*)(ws + off); off += 1536 * 512 * 2;
  __hip_bfloat16* wp    = (__hip_bfloat16*)(ws + off); off += 512 * 512 * 2;
  float*          biasc = (float*)(ws + off);          off += 8192;
  __hip_bfloat16* q_ws  = (__hip_bfloat16*)(ws + off); off += (size_t)BH_ * 6144 * 2;
  __hip_bfloat16* k_ws  = (__hip_bfloat16*)(ws + off); off += (size_t)BH_ * 6144 * 2;
  __hip_bfloat16* vt_ws = (__hip_bfloat16*)(ws + off); off += (size_t)BH_ * 6144 * 2;
  __hip_bfloat16* yb = xb;  // alias: xb fully consumed by gemm_qkv before attn writes y

  if (ws_size < off) return;

  convert_x_kernel<<<2048, 256, 0, stream>>>(x, xb, BT_ * 512 / 4);
  convert_w_kernel<<<1024, 256, 0, stream>>>(Wq, Wk, Wv, Wp, bq, bk, bv, wqkv, wp, biasc);
  zero_pads_kernel<<<2048, 256, 0, stream>>>(q_ws, k_ws, vt_ws);
  // qkv: 128x128 tiles -> 348 x 12 = 4176 blocks (div by 8)
  gemmr_kernel<0><<<4176, 256, 0, stream>>>(xb, wqkv, biasc, 12, q_ws, k_ws, vt_ws);
  attn_kernel<<<BH_, 256, 0, stream>>>(q_ws, k_ws, vt_ws, yb);
  // proj: 128x128 tiles -> 348 x 4 = 1392 blocks (div by 8)
  gemmr_kernel<1><<<1392, 256, 0, stream>>>(yb, wp, bp, 4, out, nullptr, nullptr);
}